// Round 1
// baseline (1903.128 us; speedup 1.0000x reference)
//
#include <hip/hip_runtime.h>
#include <math.h>

#define ACT_SHIFT_F (-13.8155095579637744f)
#define TN 0.05f
#define TF 2.0f

// One block per ray. Phase 1: thread = sample (256 samples): trilerp density,
// alpha, transmittance scan, trilerp 12-ch features + view embedding -> x[40]
// rows in LDS. Phase 2: thread = (neuron j in [0,128), sample slot sb in {0,1}):
// per-neuron weight columns live in registers (compile-time indexed), activations
// broadcast from LDS, h0 exchanged through a tiny LDS buffer, layer-2 (N=3)
// fused as a shuffle-reduce epilogue accumulated per ray.
__global__ __launch_bounds__(256, 2)
void dvgo_render(const float* __restrict__ rays_o,
                 const float* __restrict__ rays_d,
                 const float* __restrict__ dens,
                 const float* __restrict__ k0,
                 const float* __restrict__ w0,
                 const float* __restrict__ b0,
                 const float* __restrict__ w1,
                 const float* __restrict__ b1,
                 const float* __restrict__ w2,
                 const float* __restrict__ b2,
                 float* __restrict__ out)
{
    __shared__ float xs[256 * 40];     // x rows, padded 39->40 (16B aligned rows)
    __shared__ float sh[256];          // scan buffer
    __shared__ float wts[256];         // per-sample weights
    __shared__ float h0s[2][128];      // h0 exchange, per sample slot
    __shared__ float red[2][2][3];     // [slot][wave-half][channel] partial rgb
    __shared__ float rgbacc[6];        // [slot*3+c] running weighted rgb
    __shared__ float ainv_sh;

    const int r   = blockIdx.x;
    const int tid = threadIdx.x;

    // ---------------- phase 1: thread = sample ----------------
    {
        const int s = tid;
        const float ox = rays_o[r*3+0], oy = rays_o[r*3+1], oz = rays_o[r*3+2];
        const float dxr = rays_d[r*3+0], dyr = rays_d[r*3+1], dzr = rays_d[r*3+2];
        const float rn = rsqrtf(dxr*dxr + dyr*dyr + dzr*dzr);
        const float vx = dxr*rn, vy = dyr*rn, vz = dzr*rn;
        const float t = TN + (TF - TN) * (1.0f/255.0f) * (float)s;
        const float px = ox + vx*t, py = oy + vy*t, pz = oz + vz*t;
        const bool inbox = (px >= -1.f) && (px <= 1.f) &&
                           (py >= -1.f) && (py <= 1.f) &&
                           (pz >= -1.f) && (pz <= 1.f);

        // voxel coords (clip exactly like the reference)
        const float ix = fminf(fmaxf((px + 1.f) * 79.5f, 0.f), 159.f);
        const float iy = fminf(fmaxf((py + 1.f) * 79.5f, 0.f), 159.f);
        const float iz = fminf(fmaxf((pz + 1.f) * 79.5f, 0.f), 159.f);
        const int x0 = min((int)ix, 158);
        const int y0 = min((int)iy, 158);
        const int z0 = min((int)iz, 158);
        const float fx = ix - (float)x0, fy = iy - (float)y0, fz = iz - (float)z0;
        const float gx = 1.f - fx, gy = 1.f - fy, gz = 1.f - fz;
        const int DX = 160*160, DY = 160;
        const int base = (x0*160 + y0)*160 + z0;
        const float w000 = gx*gy*gz, w100 = fx*gy*gz, w010 = gx*fy*gz, w001 = gx*gy*fz;
        const float w110 = fx*fy*gz, w101 = fx*gy*fz, w011 = gx*fy*fz, w111 = fx*fy*fz;

        float alpha = 0.f;
        if (inbox) {
            const float d =
                dens[base          ]*w000 + dens[base+DX      ]*w100 +
                dens[base+DY       ]*w010 + dens[base+1       ]*w001 +
                dens[base+DX+DY    ]*w110 + dens[base+DX+1    ]*w101 +
                dens[base+DY+1     ]*w011 + dens[base+DX+DY+1 ]*w111;
            const float e  = expf(d + ACT_SHIFT_F);
            const float op = 1.f + e;
            // 1 - (1+e)^(-1/2) computed cancellation-free
            alpha = e / (op + sqrtf(op));
        }

        sh[s] = 1.f - alpha;
        __syncthreads();
        #pragma unroll
        for (int off = 1; off < 256; off <<= 1) {
            const float v = (s >= off) ? sh[s - off] : 1.f;
            __syncthreads();
            sh[s] *= v;
            __syncthreads();
        }
        const float Texcl = (s == 0) ? 1.f : sh[s-1];
        wts[s] = alpha * Texcl;
        if (s == 255) ainv_sh = sh[255];
        if (s < 6) rgbacc[s] = 0.f;

        float* xrow = &xs[s*40];
        if (inbox) {
            #pragma unroll
            for (int c = 0; c < 12; ++c) {
                const float* g = k0 + c*4096000 + base;
                xrow[c] = g[0       ]*w000 + g[DX     ]*w100 +
                          g[DY      ]*w010 + g[1      ]*w001 +
                          g[DX+DY   ]*w110 + g[DX+1   ]*w101 +
                          g[DY+1    ]*w011 + g[DX+DY+1]*w111;
            }
        } else {
            #pragma unroll
            for (int c = 0; c < 12; ++c) xrow[c] = 0.f;
        }
        xrow[12] = vx; xrow[13] = vy; xrow[14] = vz;
        const float v3[3] = {vx, vy, vz};
        #pragma unroll
        for (int i = 0; i < 3; ++i) {
            #pragma unroll
            for (int p = 0; p < 4; ++p) {
                const float a = v3[i] * (float)(1 << p);
                float sn, cn;
                __sincosf(a, &sn, &cn);
                xrow[15 + i*4 + p] = sn;
                xrow[27 + i*4 + p] = cn;
            }
        }
        xrow[39] = 0.f;
    }
    __syncthreads();

    // ---------------- phase 2: thread = (neuron, sample-slot) ----------------
    const int j  = tid & 127;
    const int sb = tid >> 7;

    // per-neuron weight columns in registers (compile-time indexed everywhere)
    float w0c[40];
    #pragma unroll
    for (int k = 0; k < 39; ++k) w0c[k] = w0[k*128 + j];
    w0c[39] = 0.f;
    float w1c[128];
    #pragma unroll
    for (int k = 0; k < 128; ++k) w1c[k] = w1[k*128 + j];
    const float b0j = b0[j], b1j = b1[j];
    const float w2r0 = w2[j*3+0], w2r1 = w2[j*3+1], w2r2 = w2[j*3+2];
    const float b20 = b2[0], b21 = b2[1], b22 = b2[2];

    const int lane  = tid & 63;
    const int halfw = (tid >> 6) & 1;

    for (int it = 0; it < 128; ++it) {
        const int s = it*2 + sb;

        // layer 0: h0_j = relu(b0_j + sum_k x[k] * w0[k][j])
        const float4* xrow4 = (const float4*)(&xs[s*40]);
        float acc = b0j;
        #pragma unroll
        for (int q = 0; q < 10; ++q) {
            const float4 v = xrow4[q];
            acc = fmaf(v.x, w0c[q*4+0], acc);
            acc = fmaf(v.y, w0c[q*4+1], acc);
            acc = fmaf(v.z, w0c[q*4+2], acc);
            acc = fmaf(v.w, w0c[q*4+3], acc);
        }
        h0s[sb][j] = fmaxf(acc, 0.f);
        __syncthreads();

        // layer 1: h1_j = relu(b1_j + sum_k h0[k] * w1[k][j])
        float acc1 = b1j;
        const float4* h4 = (const float4*)(&h0s[sb][0]);
        #pragma unroll
        for (int q = 0; q < 32; ++q) {
            const float4 v = h4[q];
            acc1 = fmaf(v.x, w1c[q*4+0], acc1);
            acc1 = fmaf(v.y, w1c[q*4+1], acc1);
            acc1 = fmaf(v.z, w1c[q*4+2], acc1);
            acc1 = fmaf(v.w, w1c[q*4+3], acc1);
        }
        const float hv = fmaxf(acc1, 0.f);

        // layer 2 fused: rgb_c partial = h1_j * w2[j][c], reduce over j
        float p0 = hv * w2r0, p1 = hv * w2r1, p2 = hv * w2r2;
        #pragma unroll
        for (int off = 32; off > 0; off >>= 1) {
            p0 += __shfl_down(p0, off);
            p1 += __shfl_down(p1, off);
            p2 += __shfl_down(p2, off);
        }
        if (lane == 0) {
            red[sb][halfw][0] = p0;
            red[sb][halfw][1] = p1;
            red[sb][halfw][2] = p2;
        }
        __syncthreads();
        if (tid == sb*128) {   // tid 0 (slot 0) and tid 128 (slot 1)
            const float r0 = red[sb][0][0] + red[sb][1][0] + b20;
            const float r1 = red[sb][0][1] + red[sb][1][1] + b21;
            const float r2 = red[sb][0][2] + red[sb][1][2] + b22;
            const float wgt = wts[s];
            rgbacc[sb*3+0] += wgt / (1.f + expf(-r0));
            rgbacc[sb*3+1] += wgt / (1.f + expf(-r1));
            rgbacc[sb*3+2] += wgt / (1.f + expf(-r2));
        }
        // next-iter h0s/red writes are fenced by the barriers above (see analysis)
    }
    __syncthreads();
    if (tid < 3) out[r*3 + tid] = rgbacc[tid] + rgbacc[3 + tid] + ainv_sh;
}

extern "C" void kernel_launch(void* const* d_in, const int* in_sizes, int n_in,
                              void* d_out, int out_size, void* d_ws, size_t ws_size,
                              hipStream_t stream)
{
    const float* rays_o = (const float*)d_in[0];
    const float* rays_d = (const float*)d_in[1];
    const float* dens   = (const float*)d_in[2];
    const float* k0     = (const float*)d_in[3];
    const float* w0     = (const float*)d_in[4];
    const float* b0     = (const float*)d_in[5];
    const float* w1     = (const float*)d_in[6];
    const float* b1     = (const float*)d_in[7];
    const float* w2     = (const float*)d_in[8];
    const float* b2     = (const float*)d_in[9];
    float* out = (float*)d_out;

    const int N = in_sizes[0] / 3;   // 4096 rays
    dvgo_render<<<dim3(N), dim3(256), 0, stream>>>(
        rays_o, rays_d, dens, k0, w0, b0, w1, b1, w2, b2, out);
}

// Round 2
// 1056.986 us; speedup vs baseline: 1.8005x; 1.8005x over previous
//
#include <hip/hip_runtime.h>
#include <hip/hip_bf16.h>
#include <math.h>

#define ACT_SHIFT_F (-13.8155095579637744f)
#define GRID_VOX 4096000
#define GP_BYTES  (GRID_VOX * 32)          // bf16 x16 channels per voxel
#define W0P_OFF   GP_BYTES                 // 8 frags  * 1024B
#define W1P_OFF   (W0P_OFF + 8 * 1024)     // 32 frags * 1024B
#define W2P_OFF   (W1P_OFF + 32 * 1024)    // 4 frags  * 1024B
#define WS_NEED   ((size_t)(W2P_OFF + 4 * 1024))

typedef __bf16 bf16x8 __attribute__((ext_vector_type(8)));
typedef float  f32x4  __attribute__((ext_vector_type(4)));

__device__ __forceinline__ float bfu(unsigned short b) {
    return __uint_as_float(((unsigned int)b) << 16);
}
__device__ __forceinline__ unsigned short f2bf(float x) {   // RNE
    unsigned int u = __float_as_uint(x);
    u += 0x7fffu + ((u >> 16) & 1u);
    return (unsigned short)(u >> 16);
}
#define UNPK(u, lo, hi) { lo = __uint_as_float((u) << 16); hi = __uint_as_float((u) & 0xffff0000u); }

__device__ __constant__ int offv_c[8] = {0, 1, 160, 161, 25600, 25601, 25760, 25761};

// ---------------- repack: density+k0 -> interleaved bf16 [vox][16] ----------------
__global__ void repack_grid(const float* __restrict__ dens, const float* __restrict__ k0,
                            unsigned short* __restrict__ gp)
{
    const int v = blockIdx.x * 256 + threadIdx.x;
    if (v >= GRID_VOX) return;
    unsigned short s[16];
    s[0] = f2bf(dens[v]);
    #pragma unroll
    for (int c = 0; c < 12; ++c) s[1 + c] = f2bf(k0[c * GRID_VOX + v]);
    s[13] = 0; s[14] = 0; s[15] = 0;
    uint4 q0, q1;
    q0.x = s[0] | (s[1] << 16);  q0.y = s[2] | (s[3] << 16);
    q0.z = s[4] | (s[5] << 16);  q0.w = s[6] | (s[7] << 16);
    q1.x = s[8] | (s[9] << 16);  q1.y = s[10] | (s[11] << 16);
    q1.z = s[12] | (s[13] << 16); q1.w = s[14] | (s[15] << 16);
    uint4* dst = (uint4*)(gp + (size_t)v * 16);
    dst[0] = q0; dst[1] = q1;
}

// ---------------- repack: W0/W1/W2 -> MFMA B-fragment order ----------------
// B-frag (16x16x32): lane l holds B[k = (l>>4)*8 + j][n = l&15], j=0..7 (16B).
__global__ void repack_w(const float* __restrict__ w0, const float* __restrict__ w1,
                         const float* __restrict__ w2, unsigned short* __restrict__ wp)
{
    const int t = blockIdx.x * 256 + threadIdx.x;
    if (t >= 44 * 64) return;
    const int f = t >> 6, l = t & 63;
    const int n16 = l & 15, kg = l >> 4;
    unsigned short v[8];
    if (f < 8) {                       // W0: ntile=f, K=32 (feature rows 0..11 real)
        const int n = f * 16 + n16;
        #pragma unroll
        for (int j = 0; j < 8; ++j) {
            const int k = kg * 8 + j;
            v[j] = (k < 12) ? f2bf(w0[k * 128 + n]) : (unsigned short)0;
        }
    } else if (f < 40) {               // W1: frag (nt, ks)
        const int ff = f - 8, nt = ff >> 2, ks = ff & 3;
        const int n = nt * 16 + n16;
        #pragma unroll
        for (int j = 0; j < 8; ++j) {
            const int k = ks * 32 + kg * 8 + j;
            v[j] = f2bf(w1[k * 128 + n]);
        }
    } else {                           // W2: N=16 (cols 0..2 real), frag ks
        const int ks = f - 40;
        #pragma unroll
        for (int j = 0; j < 8; ++j) {
            const int k = ks * 32 + kg * 8 + j;
            v[j] = (n16 < 3) ? f2bf(w2[k * 3 + n16]) : (unsigned short)0;
        }
    }
    uint4 q;
    q.x = v[0] | (v[1] << 16); q.y = v[2] | (v[3] << 16);
    q.z = v[4] | (v[5] << 16); q.w = v[6] | (v[7] << 16);
    *(uint4*)(wp + f * 512 + l * 8) = q;
}

// ---------------- main render: one block per ray ----------------
__global__ __launch_bounds__(256, 3)
void dvgo_mfma(const float* __restrict__ rays_o, const float* __restrict__ rays_d,
               const float* __restrict__ w0, const float* __restrict__ b0,
               const float* __restrict__ b1, const float* __restrict__ b2,
               const unsigned short* __restrict__ gp,   // packed grid
               const unsigned short* __restrict__ wpk,  // packed weights (at W0P_OFF)
               float* __restrict__ out)
{
    __shared__ unsigned short Xs[128 * 40];   // 12 feat + 20 zero pad (+8 cpad), stride 40 bf16
    __shared__ unsigned short Hs[128 * 136];  // 128 + 8 pad, stride 136 bf16
    __shared__ float sh[256];
    __shared__ float wts[256];
    __shared__ float b0eff[128];
    __shared__ float b1s[128];
    __shared__ float vemb[28];
    __shared__ float red[4][3];
    __shared__ float b2s[3];
    __shared__ float ainv_sh;

    const int r = blockIdx.x, t = threadIdx.x;
    const int l = t & 63, wv = t >> 6;
    const int col = l & 15, rg = l >> 4;

    const float ox = rays_o[r*3+0], oy = rays_o[r*3+1], oz = rays_o[r*3+2];
    const float dxr = rays_d[r*3+0], dyr = rays_d[r*3+1], dzr = rays_d[r*3+2];
    const float rn = rsqrtf(dxr*dxr + dyr*dyr + dzr*dzr);
    const float vx = dxr*rn, vy = dyr*rn, vz = dzr*rn;

    // ---- phase 0: vemb, biases, density->alpha->scan->wts, X zero-pad ----
    if (t < 27) {
        float val;
        if (t < 3) val = (t == 0) ? vx : ((t == 1) ? vy : vz);
        else {
            int q = t - 3;
            const bool is_sin = q < 12;
            if (!is_sin) q -= 12;
            const int i = q >> 2, p = q & 3;
            const float a = ((i == 0) ? vx : ((i == 1) ? vy : vz)) * (float)(1 << p);
            val = is_sin ? sinf(a) : cosf(a);
        }
        vemb[t] = val;
    }
    if (t < 3)   b2s[t] = b2[t];
    if (t < 128) b1s[t] = b1[t];

    float alpha = 0.f;
    {
        const int s = t;
        const float tp = 0.05f + (1.95f / 255.f) * (float)s;
        const float px = ox + vx*tp, py = oy + vy*tp, pz = oz + vz*tp;
        const bool inbox = (px >= -1.f) & (px <= 1.f) & (py >= -1.f) & (py <= 1.f) &
                           (pz >= -1.f) & (pz <= 1.f);
        if (inbox) {
            const float ix = fminf(fmaxf((px + 1.f) * 79.5f, 0.f), 159.f);
            const float iy = fminf(fmaxf((py + 1.f) * 79.5f, 0.f), 159.f);
            const float iz = fminf(fmaxf((pz + 1.f) * 79.5f, 0.f), 159.f);
            const int x0 = min((int)ix, 158), y0 = min((int)iy, 158), z0 = min((int)iz, 158);
            const float fx = ix - x0, fy = iy - y0, fz = iz - z0;
            const float gx = 1.f - fx, gy = 1.f - fy, gz = 1.f - fz;
            const int base = (x0 * 160 + y0) * 160 + z0;
            float w8[8];
            w8[0]=gx*gy*gz; w8[1]=gx*gy*fz; w8[2]=gx*fy*gz; w8[3]=gx*fy*fz;
            w8[4]=fx*gy*gz; w8[5]=fx*gy*fz; w8[6]=fx*fy*gz; w8[7]=fx*fy*fz;
            float d = 0.f;
            #pragma unroll
            for (int cn = 0; cn < 8; ++cn)
                d = fmaf(w8[cn], bfu(gp[(size_t)(base + offv_c[cn]) * 16]), d);
            const float e = expf(d + ACT_SHIFT_F);
            const float op = 1.f + e;
            alpha = e / (op + sqrtf(op));    // 1-(1+e)^(-1/2), cancellation-free
        }
        sh[t] = 1.f - alpha;
    }
    __syncthreads();

    if (t < 128) {                       // fold view embedding into layer-0 bias
        float a = b0[t];
        #pragma unroll
        for (int k = 0; k < 27; ++k) a = fmaf(vemb[k], w0[(12 + k) * 128 + t], a);
        b0eff[t] = a;
    }
    // X zero region: cols 12..31 (dwords 6..15 of each 20-dword row); cols 32..39 never read
    for (int i = t; i < 128 * 10; i += 256) {
        const int row = i / 10, c = i % 10;
        ((unsigned int*)Xs)[row * 20 + 6 + c] = 0u;
    }

    #pragma unroll
    for (int off = 1; off < 256; off <<= 1) {   // Hillis-Steele cumprod
        const float v = (t >= off) ? sh[t - off] : 1.f;
        __syncthreads();
        sh[t] *= v;
        __syncthreads();
    }
    wts[t] = alpha * ((t == 0) ? 1.f : sh[t - 1]);
    if (t == 255) ainv_sh = sh[255];

    const unsigned short* w0p = wpk;
    const unsigned short* w1p = wpk + 8 * 512;
    const unsigned short* w2p = wpk + 40 * 512;
    const uint4* gq = (const uint4*)gp;

    float pacc = 0.f;   // per-lane weighted-rgb accumulator (cols 0..2 meaningful)

    for (int ck = 0; ck < 2; ++ck) {
        // ---- phase A: feature gather -> X rows (bf16), thread=(sample, half) ----
        {
            const int sl = t >> 1, hf = t & 1;
            const int s = ck * 128 + sl;
            const float tp = 0.05f + (1.95f / 255.f) * (float)s;
            const float px = ox + vx*tp, py = oy + vy*tp, pz = oz + vz*tp;
            const bool inbox = (px >= -1.f) & (px <= 1.f) & (py >= -1.f) & (py <= 1.f) &
                               (pz >= -1.f) & (pz <= 1.f);
            unsigned short* xrow = &Xs[sl * 40];
            if (inbox) {
                const float ix = fminf(fmaxf((px + 1.f) * 79.5f, 0.f), 159.f);
                const float iy = fminf(fmaxf((py + 1.f) * 79.5f, 0.f), 159.f);
                const float iz = fminf(fmaxf((pz + 1.f) * 79.5f, 0.f), 159.f);
                const int x0 = min((int)ix, 158), y0 = min((int)iy, 158), z0 = min((int)iz, 158);
                const float fx = ix - x0, fy = iy - y0, fz = iz - z0;
                const float gx = 1.f - fx, gy = 1.f - fy, gz = 1.f - fz;
                const int base = (x0 * 160 + y0) * 160 + z0;
                float w8[8];
                w8[0]=gx*gy*gz; w8[1]=gx*gy*fz; w8[2]=gx*fy*gz; w8[3]=gx*fy*fz;
                w8[4]=fx*gy*gz; w8[5]=fx*gy*fz; w8[6]=fx*fy*gz; w8[7]=fx*fy*fz;
                float a0=0,a1=0,a2=0,a3=0,a4=0,a5=0,a6=0,a7=0;
                #pragma unroll
                for (int cn = 0; cn < 8; ++cn) {
                    const uint4 q = gq[(size_t)(base + offv_c[cn]) * 2 + hf];
                    float f0,f1,f2,f3,f4,f5,f6,f7;
                    UNPK(q.x, f0, f1); UNPK(q.y, f2, f3);
                    UNPK(q.z, f4, f5); UNPK(q.w, f6, f7);
                    const float wc = w8[cn];
                    a0=fmaf(wc,f0,a0); a1=fmaf(wc,f1,a1); a2=fmaf(wc,f2,a2); a3=fmaf(wc,f3,a3);
                    a4=fmaf(wc,f4,a4); a5=fmaf(wc,f5,a5); a6=fmaf(wc,f6,a6); a7=fmaf(wc,f7,a7);
                }
                if (hf == 0) {   // slots 0..7 = [dens, feat0..6] -> x cols 0..6
                    xrow[0]=f2bf(a1); xrow[1]=f2bf(a2); xrow[2]=f2bf(a3); xrow[3]=f2bf(a4);
                    xrow[4]=f2bf(a5); xrow[5]=f2bf(a6); xrow[6]=f2bf(a7);
                } else {         // slots 8..15 = [feat7..11, pad] -> x cols 7..11
                    xrow[7]=f2bf(a0); xrow[8]=f2bf(a1); xrow[9]=f2bf(a2);
                    xrow[10]=f2bf(a3); xrow[11]=f2bf(a4);
                }
            } else {
                if (hf == 0) {
                    #pragma unroll
                    for (int j = 0; j < 7; ++j) xrow[j] = 0;
                } else {
                    #pragma unroll
                    for (int j = 7; j < 12; ++j) xrow[j] = 0;
                }
            }
        }
        __syncthreads();

        const int row0 = wv * 32;   // this wave owns sample-rows [row0, row0+32)

        // ---- layer 0: H0 = relu(X*W0 + b0eff), K=32 ----
        {
            bf16x8 A0[2];
            #pragma unroll
            for (int mt = 0; mt < 2; ++mt)
                A0[mt] = *(const bf16x8*)(&Xs[(row0 + mt * 16 + col) * 40 + rg * 8]);
            #pragma unroll
            for (int nt = 0; nt < 8; ++nt) {
                const bf16x8 B = *(const bf16x8*)(w0p + nt * 512 + l * 8);
                const float bias = b0eff[nt * 16 + col];
                #pragma unroll
                for (int mt = 0; mt < 2; ++mt) {
                    f32x4 acc = {0.f, 0.f, 0.f, 0.f};
                    acc = __builtin_amdgcn_mfma_f32_16x16x32_bf16(A0[mt], B, acc, 0, 0, 0);
                    #pragma unroll
                    for (int q = 0; q < 4; ++q) {
                        const float v  = fmaxf(acc[q] + bias, 0.f);
                        const float vo = __shfl_xor(v, 1);
                        if ((l & 1) == 0) {
                            const int row = row0 + mt * 16 + rg * 4 + q;
                            const unsigned int pk = (unsigned int)f2bf(v) |
                                                    ((unsigned int)f2bf(vo) << 16);
                            *(unsigned int*)(&Hs[row * 136 + nt * 16 + col]) = pk;
                        }
                    }
                }
            }
        }
        __syncthreads();

        // ---- layer 1: H1 = relu(H0*W1 + b1), K=128, in-place rewrite ----
        {
            bf16x8 A1[2][4];
            #pragma unroll
            for (int mt = 0; mt < 2; ++mt)
                #pragma unroll
                for (int ks = 0; ks < 4; ++ks)
                    A1[mt][ks] = *(const bf16x8*)(&Hs[(row0 + mt * 16 + col) * 136 + ks * 32 + rg * 8]);
            f32x4 acc1[2][8];
            #pragma unroll
            for (int nt = 0; nt < 8; ++nt) {
                bf16x8 Bk[4];
                #pragma unroll
                for (int ks = 0; ks < 4; ++ks)
                    Bk[ks] = *(const bf16x8*)(w1p + (nt * 4 + ks) * 512 + l * 8);
                #pragma unroll
                for (int mt = 0; mt < 2; ++mt) {
                    f32x4 acc = {0.f, 0.f, 0.f, 0.f};
                    #pragma unroll
                    for (int ks = 0; ks < 4; ++ks)
                        acc = __builtin_amdgcn_mfma_f32_16x16x32_bf16(A1[mt][ks], Bk[ks], acc, 0, 0, 0);
                    acc1[mt][nt] = acc;
                }
            }
            __syncthreads();
            #pragma unroll
            for (int nt = 0; nt < 8; ++nt) {
                const float bias = b1s[nt * 16 + col];
                #pragma unroll
                for (int mt = 0; mt < 2; ++mt) {
                    #pragma unroll
                    for (int q = 0; q < 4; ++q) {
                        const float v  = fmaxf(acc1[mt][nt][q] + bias, 0.f);
                        const float vo = __shfl_xor(v, 1);
                        if ((l & 1) == 0) {
                            const int row = row0 + mt * 16 + rg * 4 + q;
                            const unsigned int pk = (unsigned int)f2bf(v) |
                                                    ((unsigned int)f2bf(vo) << 16);
                            *(unsigned int*)(&Hs[row * 136 + nt * 16 + col]) = pk;
                        }
                    }
                }
            }
        }
        __syncthreads();

        // ---- layer 2 + epilogue: rgb = sigmoid(H1*W2 + b2); pacc += wts*rgb ----
        {
            bf16x8 Bk[4];
            #pragma unroll
            for (int ks = 0; ks < 4; ++ks)
                Bk[ks] = *(const bf16x8*)(w2p + ks * 512 + l * 8);
            const float bias2 = (col < 3) ? b2s[col] : 0.f;
            #pragma unroll
            for (int mt = 0; mt < 2; ++mt) {
                bf16x8 A2[4];
                #pragma unroll
                for (int ks = 0; ks < 4; ++ks)
                    A2[ks] = *(const bf16x8*)(&Hs[(row0 + mt * 16 + col) * 136 + ks * 32 + rg * 8]);
                f32x4 acc = {0.f, 0.f, 0.f, 0.f};
                #pragma unroll
                for (int ks = 0; ks < 4; ++ks)
                    acc = __builtin_amdgcn_mfma_f32_16x16x32_bf16(A2[ks], Bk[ks], acc, 0, 0, 0);
                #pragma unroll
                for (int q = 0; q < 4; ++q) {
                    const float rv = acc[q] + bias2;
                    const float sg = 1.f / (1.f + expf(-rv));
                    const int srow = ck * 128 + row0 + mt * 16 + rg * 4 + q;
                    pacc = fmaf(wts[srow], sg, pacc);
                }
            }
        }
        __syncthreads();   // Xs/Hs safe to rewrite next chunk
    }

    // reduce pacc over the 4 row-groups (lanes sharing a column)
    pacc += __shfl_xor(pacc, 16);
    pacc += __shfl_xor(pacc, 32);
    if (rg == 0 && col < 3) red[wv][col] = pacc;
    __syncthreads();
    if (t < 3) out[r * 3 + t] = red[0][t] + red[1][t] + red[2][t] + red[3][t] + ainv_sh;
}

// ---------------- fallback (round-1 kernel) if ws too small ----------------
__global__ __launch_bounds__(256, 2)
void dvgo_render(const float* __restrict__ rays_o, const float* __restrict__ rays_d,
                 const float* __restrict__ dens, const float* __restrict__ k0,
                 const float* __restrict__ w0, const float* __restrict__ b0,
                 const float* __restrict__ w1, const float* __restrict__ b1,
                 const float* __restrict__ w2, const float* __restrict__ b2,
                 float* __restrict__ out)
{
    __shared__ float xs[256 * 40];
    __shared__ float sh[256];
    __shared__ float wts[256];
    __shared__ float h0s[2][128];
    __shared__ float red[2][2][3];
    __shared__ float rgbacc[6];
    __shared__ float ainv_sh;

    const int r = blockIdx.x, tid = threadIdx.x;
    {
        const int s = tid;
        const float ox = rays_o[r*3+0], oy = rays_o[r*3+1], oz = rays_o[r*3+2];
        const float dxr = rays_d[r*3+0], dyr = rays_d[r*3+1], dzr = rays_d[r*3+2];
        const float rn = rsqrtf(dxr*dxr + dyr*dyr + dzr*dzr);
        const float vx = dxr*rn, vy = dyr*rn, vz = dzr*rn;
        const float t = 0.05f + 1.95f * (1.0f/255.0f) * (float)s;
        const float px = ox + vx*t, py = oy + vy*t, pz = oz + vz*t;
        const bool inbox = (px >= -1.f) && (px <= 1.f) && (py >= -1.f) && (py <= 1.f) &&
                           (pz >= -1.f) && (pz <= 1.f);
        const float ix = fminf(fmaxf((px + 1.f) * 79.5f, 0.f), 159.f);
        const float iy = fminf(fmaxf((py + 1.f) * 79.5f, 0.f), 159.f);
        const float iz = fminf(fmaxf((pz + 1.f) * 79.5f, 0.f), 159.f);
        const int x0 = min((int)ix, 158), y0 = min((int)iy, 158), z0 = min((int)iz, 158);
        const float fx = ix - x0, fy = iy - y0, fz = iz - z0;
        const float gx = 1.f - fx, gy = 1.f - fy, gz = 1.f - fz;
        const int DX = 25600, DY = 160;
        const int base = (x0*160 + y0)*160 + z0;
        const float w000=gx*gy*gz, w100=fx*gy*gz, w010=gx*fy*gz, w001=gx*gy*fz;
        const float w110=fx*fy*gz, w101=fx*gy*fz, w011=gx*fy*fz, w111=fx*fy*fz;
        float alpha = 0.f;
        if (inbox) {
            const float d = dens[base]*w000 + dens[base+DX]*w100 + dens[base+DY]*w010 +
                            dens[base+1]*w001 + dens[base+DX+DY]*w110 + dens[base+DX+1]*w101 +
                            dens[base+DY+1]*w011 + dens[base+DX+DY+1]*w111;
            const float e = expf(d + ACT_SHIFT_F);
            const float op = 1.f + e;
            alpha = e / (op + sqrtf(op));
        }
        sh[s] = 1.f - alpha;
        __syncthreads();
        #pragma unroll
        for (int off = 1; off < 256; off <<= 1) {
            const float v = (s >= off) ? sh[s - off] : 1.f;
            __syncthreads();
            sh[s] *= v;
            __syncthreads();
        }
        wts[s] = alpha * ((s == 0) ? 1.f : sh[s-1]);
        if (s == 255) ainv_sh = sh[255];
        if (s < 6) rgbacc[s] = 0.f;
        float* xrow = &xs[s*40];
        if (inbox) {
            #pragma unroll
            for (int c = 0; c < 12; ++c) {
                const float* g = k0 + c*4096000 + base;
                xrow[c] = g[0]*w000 + g[DX]*w100 + g[DY]*w010 + g[1]*w001 +
                          g[DX+DY]*w110 + g[DX+1]*w101 + g[DY+1]*w011 + g[DX+DY+1]*w111;
            }
        } else {
            #pragma unroll
            for (int c = 0; c < 12; ++c) xrow[c] = 0.f;
        }
        xrow[12]=vx; xrow[13]=vy; xrow[14]=vz;
        const float v3[3] = {vx, vy, vz};
        #pragma unroll
        for (int i = 0; i < 3; ++i)
            #pragma unroll
            for (int p = 0; p < 4; ++p) {
                const float a = v3[i] * (float)(1 << p);
                xrow[15 + i*4 + p] = sinf(a);
                xrow[27 + i*4 + p] = cosf(a);
            }
        xrow[39] = 0.f;
    }
    __syncthreads();
    const int j = tid & 127, sb = tid >> 7;
    float w0c[40];
    #pragma unroll
    for (int k = 0; k < 39; ++k) w0c[k] = w0[k*128 + j];
    w0c[39] = 0.f;
    float w1c[128];
    #pragma unroll
    for (int k = 0; k < 128; ++k) w1c[k] = w1[k*128 + j];
    const float b0j = b0[j], b1j = b1[j];
    const float w2r0 = w2[j*3+0], w2r1 = w2[j*3+1], w2r2 = w2[j*3+2];
    const float b20 = b2[0], b21 = b2[1], b22 = b2[2];
    const int lane = tid & 63, halfw = (tid >> 6) & 1;
    for (int it = 0; it < 128; ++it) {
        const int s = it*2 + sb;
        const float4* xrow4 = (const float4*)(&xs[s*40]);
        float acc = b0j;
        #pragma unroll
        for (int q = 0; q < 10; ++q) {
            const float4 v = xrow4[q];
            acc = fmaf(v.x, w0c[q*4+0], acc); acc = fmaf(v.y, w0c[q*4+1], acc);
            acc = fmaf(v.z, w0c[q*4+2], acc); acc = fmaf(v.w, w0c[q*4+3], acc);
        }
        h0s[sb][j] = fmaxf(acc, 0.f);
        __syncthreads();
        float acc1 = b1j;
        const float4* h4 = (const float4*)(&h0s[sb][0]);
        #pragma unroll
        for (int q = 0; q < 32; ++q) {
            const float4 v = h4[q];
            acc1 = fmaf(v.x, w1c[q*4+0], acc1); acc1 = fmaf(v.y, w1c[q*4+1], acc1);
            acc1 = fmaf(v.z, w1c[q*4+2], acc1); acc1 = fmaf(v.w, w1c[q*4+3], acc1);
        }
        const float hv = fmaxf(acc1, 0.f);
        float p0 = hv*w2r0, p1 = hv*w2r1, p2 = hv*w2r2;
        #pragma unroll
        for (int off = 32; off > 0; off >>= 1) {
            p0 += __shfl_down(p0, off); p1 += __shfl_down(p1, off); p2 += __shfl_down(p2, off);
        }
        if (lane == 0) { red[sb][halfw][0]=p0; red[sb][halfw][1]=p1; red[sb][halfw][2]=p2; }
        __syncthreads();
        if (tid == sb*128) {
            const float r0 = red[sb][0][0]+red[sb][1][0]+b20;
            const float r1 = red[sb][0][1]+red[sb][1][1]+b21;
            const float r2 = red[sb][0][2]+red[sb][1][2]+b22;
            const float wgt = wts[s];
            rgbacc[sb*3+0] += wgt / (1.f + expf(-r0));
            rgbacc[sb*3+1] += wgt / (1.f + expf(-r1));
            rgbacc[sb*3+2] += wgt / (1.f + expf(-r2));
        }
    }
    __syncthreads();
    if (tid < 3) out[r*3 + tid] = rgbacc[tid] + rgbacc[3 + tid] + ainv_sh;
}

extern "C" void kernel_launch(void* const* d_in, const int* in_sizes, int n_in,
                              void* d_out, int out_size, void* d_ws, size_t ws_size,
                              hipStream_t stream)
{
    const float* rays_o = (const float*)d_in[0];
    const float* rays_d = (const float*)d_in[1];
    const float* dens   = (const float*)d_in[2];
    const float* k0     = (const float*)d_in[3];
    const float* w0     = (const float*)d_in[4];
    const float* b0     = (const float*)d_in[5];
    const float* w1     = (const float*)d_in[6];
    const float* b1     = (const float*)d_in[7];
    const float* w2     = (const float*)d_in[8];
    const float* b2     = (const float*)d_in[9];
    float* out = (float*)d_out;
    const int N = in_sizes[0] / 3;

    if (ws_size >= WS_NEED) {
        unsigned short* gp  = (unsigned short*)d_ws;
        unsigned short* wpk = (unsigned short*)((char*)d_ws + W0P_OFF);
        repack_grid<<<dim3(GRID_VOX / 256), dim3(256), 0, stream>>>(dens, k0, gp);
        repack_w<<<dim3(11), dim3(256), 0, stream>>>(w0, w1, w2, wpk);
        dvgo_mfma<<<dim3(N), dim3(256), 0, stream>>>(rays_o, rays_d, w0, b0, b1, b2,
                                                     gp, wpk, out);
    } else {
        dvgo_render<<<dim3(N), dim3(256), 0, stream>>>(rays_o, rays_d, dens, k0,
                                                       w0, b0, w1, b1, w2, b2, out);
    }
}

// Round 3
// 515.241 us; speedup vs baseline: 3.6937x; 2.0514x over previous
//
#include <hip/hip_runtime.h>
#include <hip/hip_bf16.h>
#include <math.h>

#define ACT_SHIFT_F (-13.8155095579637744f)
#define GRID_VOX 4096000
#define GP_BYTES  (GRID_VOX * 32)          // bf16 x16 channels per voxel
#define W0P_OFF   GP_BYTES                 // 8 frags  * 1024B
#define W1P_OFF   (W0P_OFF + 8 * 1024)     // 32 frags * 1024B
#define W2P_OFF   (W1P_OFF + 32 * 1024)    // 4 frags  * 1024B
#define WS_NEED   ((size_t)(W2P_OFF + 4 * 1024))

typedef __bf16 bf16x8 __attribute__((ext_vector_type(8)));
typedef float  f32x4  __attribute__((ext_vector_type(4)));

__device__ __forceinline__ float bfu(unsigned short b) {
    return __uint_as_float(((unsigned int)b) << 16);
}
__device__ __forceinline__ unsigned short f2bf(float x) {   // RNE
    unsigned int u = __float_as_uint(x);
    u += 0x7fffu + ((u >> 16) & 1u);
    return (unsigned short)(u >> 16);
}
#define UNPK(u, lo, hi) { lo = __uint_as_float((u) << 16); hi = __uint_as_float((u) & 0xffff0000u); }

__device__ __constant__ int offv_c[8] = {0, 1, 160, 161, 25600, 25601, 25760, 25761};

// ---------------- repack (fused): grid -> interleaved bf16 [vox][16]; W -> B-frags ----
// blocks [0,16000): grid voxels. blocks [16000,16011): weight fragments.
__global__ void repack_all(const float* __restrict__ dens, const float* __restrict__ k0,
                           const float* __restrict__ w0, const float* __restrict__ w1,
                           const float* __restrict__ w2,
                           unsigned short* __restrict__ gp, unsigned short* __restrict__ wp)
{
    const int b = blockIdx.x;
    if (b < 16000) {
        const int v = b * 256 + threadIdx.x;
        unsigned short s[16];
        s[0] = f2bf(dens[v]);
        #pragma unroll
        for (int c = 0; c < 12; ++c) s[1 + c] = f2bf(k0[c * GRID_VOX + v]);
        s[13] = 0; s[14] = 0; s[15] = 0;
        uint4 q0, q1;
        q0.x = s[0] | (s[1] << 16);  q0.y = s[2] | (s[3] << 16);
        q0.z = s[4] | (s[5] << 16);  q0.w = s[6] | (s[7] << 16);
        q1.x = s[8] | (s[9] << 16);  q1.y = s[10] | (s[11] << 16);
        q1.z = s[12] | (s[13] << 16); q1.w = s[14] | (s[15] << 16);
        uint4* dst = (uint4*)(gp + (size_t)v * 16);
        dst[0] = q0; dst[1] = q1;
        return;
    }
    // ---- weight repack: B-frag (16x16x32): lane l holds B[k=(l>>4)*8+j][n=l&15] ----
    const int t = (b - 16000) * 256 + threadIdx.x;
    if (t >= 44 * 64) return;
    const int f = t >> 6, l = t & 63;
    const int n16 = l & 15, kg = l >> 4;
    unsigned short v[8];
    if (f < 8) {                       // W0: ntile=f, K=32 (feature rows 0..11 real)
        const int n = f * 16 + n16;
        #pragma unroll
        for (int j = 0; j < 8; ++j) {
            const int k = kg * 8 + j;
            v[j] = (k < 12) ? f2bf(w0[k * 128 + n]) : (unsigned short)0;
        }
    } else if (f < 40) {               // W1: frag (nt, ks)
        const int ff = f - 8, nt = ff >> 2, ks = ff & 3;
        const int n = nt * 16 + n16;
        #pragma unroll
        for (int j = 0; j < 8; ++j) {
            const int k = ks * 32 + kg * 8 + j;
            v[j] = f2bf(w1[k * 128 + n]);
        }
    } else {                           // W2: N=16 (cols 0..2 real), frag ks
        const int ks = f - 40;
        #pragma unroll
        for (int j = 0; j < 8; ++j) {
            const int k = ks * 32 + kg * 8 + j;
            v[j] = (n16 < 3) ? f2bf(w2[k * 3 + n16]) : (unsigned short)0;
        }
    }
    uint4 q;
    q.x = v[0] | (v[1] << 16); q.y = v[2] | (v[3] << 16);
    q.z = v[4] | (v[5] << 16); q.w = v[6] | (v[7] << 16);
    *(uint4*)(wp + f * 512 + l * 8) = q;
}

// ---------------- main render: one block per ray ----------------
// Hs rows [wv*32, wv*32+32) are WAVE-PRIVATE through L0/L1/L2 -> no intra-chunk
// barriers; L1 streams nt tiles one at a time (pragma unroll 1) so peak live
// registers stay ~110 (R2's acc1[2][8]+hoisted B spilled ~1GB of scratch).
__global__ __launch_bounds__(256, 3)
void dvgo_mfma(const float* __restrict__ rays_o, const float* __restrict__ rays_d,
               const float* __restrict__ w0, const float* __restrict__ b0,
               const float* __restrict__ b1, const float* __restrict__ b2,
               const unsigned short* __restrict__ gp,   // packed grid
               const unsigned short* __restrict__ wpk,  // packed weights
               float* __restrict__ out)
{
    __shared__ unsigned short Xs[128 * 40];   // 12 feat + 20 zero pad, stride 40 bf16
    __shared__ unsigned short Hs[128 * 136];  // 128 + 8 pad, stride 136 bf16 (272B, 16B-aligned rows)
    __shared__ float sh[256];
    __shared__ float wts[256];
    __shared__ float b0eff[128];
    __shared__ float b1s[128];
    __shared__ float vemb[28];
    __shared__ float red[4][3];
    __shared__ float b2s[3];
    __shared__ float ainv_sh;

    const int r = blockIdx.x, t = threadIdx.x;
    const int l = t & 63, wv = t >> 6;
    const int col = l & 15, rg = l >> 4;

    const float ox = rays_o[r*3+0], oy = rays_o[r*3+1], oz = rays_o[r*3+2];
    const float dxr = rays_d[r*3+0], dyr = rays_d[r*3+1], dzr = rays_d[r*3+2];
    const float rn = rsqrtf(dxr*dxr + dyr*dyr + dzr*dzr);
    const float vx = dxr*rn, vy = dyr*rn, vz = dzr*rn;

    // ---- phase 0: vemb, biases, density->alpha->scan->wts, X zero-pad ----
    if (t < 27) {
        float val;
        if (t < 3) val = (t == 0) ? vx : ((t == 1) ? vy : vz);
        else {
            int q = t - 3;
            const bool is_sin = q < 12;
            if (!is_sin) q -= 12;
            const int i = q >> 2, p = q & 3;
            const float a = ((i == 0) ? vx : ((i == 1) ? vy : vz)) * (float)(1 << p);
            val = is_sin ? sinf(a) : cosf(a);
        }
        vemb[t] = val;
    }
    if (t < 3)   b2s[t] = b2[t];
    if (t < 128) b1s[t] = b1[t];

    float alpha = 0.f;
    {
        const float tp = 0.05f + (1.95f / 255.f) * (float)t;
        const float px = ox + vx*tp, py = oy + vy*tp, pz = oz + vz*tp;
        const bool inbox = (px >= -1.f) & (px <= 1.f) & (py >= -1.f) & (py <= 1.f) &
                           (pz >= -1.f) & (pz <= 1.f);
        if (inbox) {
            const float ix = fminf(fmaxf((px + 1.f) * 79.5f, 0.f), 159.f);
            const float iy = fminf(fmaxf((py + 1.f) * 79.5f, 0.f), 159.f);
            const float iz = fminf(fmaxf((pz + 1.f) * 79.5f, 0.f), 159.f);
            const int x0 = min((int)ix, 158), y0 = min((int)iy, 158), z0 = min((int)iz, 158);
            const float fx = ix - x0, fy = iy - y0, fz = iz - z0;
            const float gx = 1.f - fx, gy = 1.f - fy, gz = 1.f - fz;
            const int base = (x0 * 160 + y0) * 160 + z0;
            float w8[8];
            w8[0]=gx*gy*gz; w8[1]=gx*gy*fz; w8[2]=gx*fy*gz; w8[3]=gx*fy*fz;
            w8[4]=fx*gy*gz; w8[5]=fx*gy*fz; w8[6]=fx*fy*gz; w8[7]=fx*fy*fz;
            float d = 0.f;
            #pragma unroll
            for (int cn = 0; cn < 8; ++cn)
                d = fmaf(w8[cn], bfu(gp[(size_t)(base + offv_c[cn]) * 16]), d);
            const float e = expf(d + ACT_SHIFT_F);
            const float op = 1.f + e;
            alpha = e / (op + sqrtf(op));    // 1-(1+e)^(-1/2), cancellation-free
        }
        sh[t] = 1.f - alpha;
    }
    __syncthreads();

    if (t < 128) {                       // fold view embedding into layer-0 bias
        float a = b0[t];
        #pragma unroll
        for (int k = 0; k < 27; ++k) a = fmaf(vemb[k], w0[(12 + k) * 128 + t], a);
        b0eff[t] = a;
    }
    // X zero region: cols 12..31 (dwords 6..15 of each 20-dword row)
    for (int i = t; i < 128 * 10; i += 256) {
        const int row = i / 10, c = i % 10;
        ((unsigned int*)Xs)[row * 20 + 6 + c] = 0u;
    }

    #pragma unroll
    for (int off = 1; off < 256; off <<= 1) {   // Hillis-Steele cumprod
        const float v = (t >= off) ? sh[t - off] : 1.f;
        __syncthreads();
        sh[t] *= v;
        __syncthreads();
    }
    wts[t] = alpha * ((t == 0) ? 1.f : sh[t - 1]);
    if (t == 255) ainv_sh = sh[255];

    const unsigned short* w0p = wpk;
    const unsigned short* w1p = wpk + 8 * 512;
    const unsigned short* w2p = wpk + 40 * 512;
    const uint4* gq = (const uint4*)gp;

    float pacc = 0.f;   // per-lane weighted-rgb accumulator (cols 0..2 meaningful)

    #pragma unroll 1
    for (int ck = 0; ck < 2; ++ck) {
        // ---- phase A: feature gather -> X rows (bf16), thread=(sample, half) ----
        {
            const int sl = t >> 1, hf = t & 1;
            const int s = ck * 128 + sl;
            const float tp = 0.05f + (1.95f / 255.f) * (float)s;
            const float px = ox + vx*tp, py = oy + vy*tp, pz = oz + vz*tp;
            const bool inbox = (px >= -1.f) & (px <= 1.f) & (py >= -1.f) & (py <= 1.f) &
                               (pz >= -1.f) & (pz <= 1.f);
            unsigned short* xrow = &Xs[sl * 40];
            if (inbox) {
                const float ix = fminf(fmaxf((px + 1.f) * 79.5f, 0.f), 159.f);
                const float iy = fminf(fmaxf((py + 1.f) * 79.5f, 0.f), 159.f);
                const float iz = fminf(fmaxf((pz + 1.f) * 79.5f, 0.f), 159.f);
                const int x0 = min((int)ix, 158), y0 = min((int)iy, 158), z0 = min((int)iz, 158);
                const float fx = ix - x0, fy = iy - y0, fz = iz - z0;
                const float gx = 1.f - fx, gy = 1.f - fy, gz = 1.f - fz;
                const int base = (x0 * 160 + y0) * 160 + z0;
                float w8[8];
                w8[0]=gx*gy*gz; w8[1]=gx*gy*fz; w8[2]=gx*fy*gz; w8[3]=gx*fy*fz;
                w8[4]=fx*gy*gz; w8[5]=fx*gy*fz; w8[6]=fx*fy*gz; w8[7]=fx*fy*fz;
                float a0=0,a1=0,a2=0,a3=0,a4=0,a5=0,a6=0,a7=0;
                #pragma unroll
                for (int cn = 0; cn < 8; ++cn) {
                    const uint4 q = gq[(size_t)(base + offv_c[cn]) * 2 + hf];
                    float f0,f1,f2,f3,f4,f5,f6,f7;
                    UNPK(q.x, f0, f1); UNPK(q.y, f2, f3);
                    UNPK(q.z, f4, f5); UNPK(q.w, f6, f7);
                    const float wc = w8[cn];
                    a0=fmaf(wc,f0,a0); a1=fmaf(wc,f1,a1); a2=fmaf(wc,f2,a2); a3=fmaf(wc,f3,a3);
                    a4=fmaf(wc,f4,a4); a5=fmaf(wc,f5,a5); a6=fmaf(wc,f6,a6); a7=fmaf(wc,f7,a7);
                }
                if (hf == 0) {   // slots 0..7 = [dens, feat0..6] -> x cols 0..6
                    xrow[0]=f2bf(a1); xrow[1]=f2bf(a2); xrow[2]=f2bf(a3); xrow[3]=f2bf(a4);
                    xrow[4]=f2bf(a5); xrow[5]=f2bf(a6); xrow[6]=f2bf(a7);
                } else {         // slots 8..15 = [feat7..11, pad] -> x cols 7..11
                    xrow[7]=f2bf(a0); xrow[8]=f2bf(a1); xrow[9]=f2bf(a2);
                    xrow[10]=f2bf(a3); xrow[11]=f2bf(a4);
                }
            } else {
                if (hf == 0) {
                    #pragma unroll
                    for (int j = 0; j < 7; ++j) xrow[j] = 0;
                } else {
                    #pragma unroll
                    for (int j = 7; j < 12; ++j) xrow[j] = 0;
                }
            }
        }
        __syncthreads();   // Xs complete (cross-wave writers)

        const int row0 = wv * 32;   // this wave owns sample-rows [row0, row0+32)

        // ---- layer 0: H0 = relu(X*W0 + b0eff), K=32; wave-private Hs writes ----
        {
            bf16x8 A0[2];
            #pragma unroll
            for (int mt = 0; mt < 2; ++mt)
                A0[mt] = *(const bf16x8*)(&Xs[(row0 + mt * 16 + col) * 40 + rg * 8]);
            #pragma unroll 1
            for (int nt = 0; nt < 8; ++nt) {
                const bf16x8 B = *(const bf16x8*)(w0p + nt * 512 + l * 8);
                const float bias = b0eff[nt * 16 + col];
                #pragma unroll
                for (int mt = 0; mt < 2; ++mt) {
                    f32x4 acc = {0.f, 0.f, 0.f, 0.f};
                    acc = __builtin_amdgcn_mfma_f32_16x16x32_bf16(A0[mt], B, acc, 0, 0, 0);
                    #pragma unroll
                    for (int q = 0; q < 4; ++q) {
                        const float v  = fmaxf(acc[q] + bias, 0.f);
                        const float vo = __shfl_xor(v, 1);
                        if ((l & 1) == 0) {
                            const int row = row0 + mt * 16 + rg * 4 + q;
                            const unsigned int pk = (unsigned int)f2bf(v) |
                                                    ((unsigned int)f2bf(vo) << 16);
                            *(unsigned int*)(&Hs[row * 136 + nt * 16 + col]) = pk;
                        }
                    }
                }
            }
        }
        // (no barrier: Hs rows are wave-private)

        // ---- layer 1: H1 = relu(H0*W1 + b1), K=128, in-place, nt streamed ----
        {
            bf16x8 A1[2][4];
            #pragma unroll
            for (int mt = 0; mt < 2; ++mt)
                #pragma unroll
                for (int ks = 0; ks < 4; ++ks)
                    A1[mt][ks] = *(const bf16x8*)(&Hs[(row0 + mt * 16 + col) * 136 + ks * 32 + rg * 8]);
            #pragma unroll 1
            for (int nt = 0; nt < 8; ++nt) {
                bf16x8 Bk[4];
                #pragma unroll
                for (int ks = 0; ks < 4; ++ks)
                    Bk[ks] = *(const bf16x8*)(w1p + (nt * 4 + ks) * 512 + l * 8);
                const float bias = b1s[nt * 16 + col];
                #pragma unroll
                for (int mt = 0; mt < 2; ++mt) {
                    f32x4 acc = {0.f, 0.f, 0.f, 0.f};
                    #pragma unroll
                    for (int ks = 0; ks < 4; ++ks)
                        acc = __builtin_amdgcn_mfma_f32_16x16x32_bf16(A1[mt][ks], Bk[ks], acc, 0, 0, 0);
                    #pragma unroll
                    for (int q = 0; q < 4; ++q) {
                        const float v  = fmaxf(acc[q] + bias, 0.f);
                        const float vo = __shfl_xor(v, 1);
                        if ((l & 1) == 0) {
                            const int row = row0 + mt * 16 + rg * 4 + q;
                            const unsigned int pk = (unsigned int)f2bf(v) |
                                                    ((unsigned int)f2bf(vo) << 16);
                            *(unsigned int*)(&Hs[row * 136 + nt * 16 + col]) = pk;
                        }
                    }
                }
            }
        }
        // (no barrier: still wave-private)

        // ---- layer 2 + epilogue: rgb = sigmoid(H1*W2 + b2); pacc += wts*rgb ----
        {
            bf16x8 Bk[4];
            #pragma unroll
            for (int ks = 0; ks < 4; ++ks)
                Bk[ks] = *(const bf16x8*)(w2p + ks * 512 + l * 8);
            const float bias2 = (col < 3) ? b2s[col] : 0.f;
            #pragma unroll
            for (int mt = 0; mt < 2; ++mt) {
                bf16x8 A2[4];
                #pragma unroll
                for (int ks = 0; ks < 4; ++ks)
                    A2[ks] = *(const bf16x8*)(&Hs[(row0 + mt * 16 + col) * 136 + ks * 32 + rg * 8]);
                f32x4 acc = {0.f, 0.f, 0.f, 0.f};
                #pragma unroll
                for (int ks = 0; ks < 4; ++ks)
                    acc = __builtin_amdgcn_mfma_f32_16x16x32_bf16(A2[ks], Bk[ks], acc, 0, 0, 0);
                #pragma unroll
                for (int q = 0; q < 4; ++q) {
                    const float rv = acc[q] + bias2;
                    const float sg = 1.f / (1.f + expf(-rv));
                    const int srow = ck * 128 + row0 + mt * 16 + rg * 4 + q;
                    pacc = fmaf(wts[srow], sg, pacc);
                }
            }
        }
        __syncthreads();   // Xs safe to rewrite next chunk (L0 readers done)
    }

    // reduce pacc over the 4 row-groups (lanes sharing a column)
    pacc += __shfl_xor(pacc, 16);
    pacc += __shfl_xor(pacc, 32);
    if (rg == 0 && col < 3) red[wv][col] = pacc;
    __syncthreads();
    if (t < 3) out[r * 3 + t] = red[0][t] + red[1][t] + red[2][t] + red[3][t] + ainv_sh;
}

// ---------------- fallback (round-1 kernel) if ws too small ----------------
__global__ __launch_bounds__(256, 2)
void dvgo_render(const float* __restrict__ rays_o, const float* __restrict__ rays_d,
                 const float* __restrict__ dens, const float* __restrict__ k0,
                 const float* __restrict__ w0, const float* __restrict__ b0,
                 const float* __restrict__ w1, const float* __restrict__ b1,
                 const float* __restrict__ w2, const float* __restrict__ b2,
                 float* __restrict__ out)
{
    __shared__ float xs[256 * 40];
    __shared__ float sh[256];
    __shared__ float wts[256];
    __shared__ float h0s[2][128];
    __shared__ float red[2][2][3];
    __shared__ float rgbacc[6];
    __shared__ float ainv_sh;

    const int r = blockIdx.x, tid = threadIdx.x;
    {
        const int s = tid;
        const float ox = rays_o[r*3+0], oy = rays_o[r*3+1], oz = rays_o[r*3+2];
        const float dxr = rays_d[r*3+0], dyr = rays_d[r*3+1], dzr = rays_d[r*3+2];
        const float rn = rsqrtf(dxr*dxr + dyr*dyr + dzr*dzr);
        const float vx = dxr*rn, vy = dyr*rn, vz = dzr*rn;
        const float t = 0.05f + 1.95f * (1.0f/255.0f) * (float)s;
        const float px = ox + vx*t, py = oy + vy*t, pz = oz + vz*t;
        const bool inbox = (px >= -1.f) && (px <= 1.f) && (py >= -1.f) && (py <= 1.f) &&
                           (pz >= -1.f) && (pz <= 1.f);
        const float ix = fminf(fmaxf((px + 1.f) * 79.5f, 0.f), 159.f);
        const float iy = fminf(fmaxf((py + 1.f) * 79.5f, 0.f), 159.f);
        const float iz = fminf(fmaxf((pz + 1.f) * 79.5f, 0.f), 159.f);
        const int x0 = min((int)ix, 158), y0 = min((int)iy, 158), z0 = min((int)iz, 158);
        const float fx = ix - x0, fy = iy - y0, fz = iz - z0;
        const float gx = 1.f - fx, gy = 1.f - fy, gz = 1.f - fz;
        const int DX = 25600, DY = 160;
        const int base = (x0*160 + y0)*160 + z0;
        const float w000=gx*gy*gz, w100=fx*gy*gz, w010=gx*fy*gz, w001=gx*gy*fz;
        const float w110=fx*fy*gz, w101=fx*gy*fz, w011=gx*fy*fz, w111=fx*fy*fz;
        float alpha = 0.f;
        if (inbox) {
            const float d = dens[base]*w000 + dens[base+DX]*w100 + dens[base+DY]*w010 +
                            dens[base+1]*w001 + dens[base+DX+DY]*w110 + dens[base+DX+1]*w101 +
                            dens[base+DY+1]*w011 + dens[base+DX+DY+1]*w111;
            const float e = expf(d + ACT_SHIFT_F);
            const float op = 1.f + e;
            alpha = e / (op + sqrtf(op));
        }
        sh[s] = 1.f - alpha;
        __syncthreads();
        #pragma unroll
        for (int off = 1; off < 256; off <<= 1) {
            const float v = (s >= off) ? sh[s - off] : 1.f;
            __syncthreads();
            sh[s] *= v;
            __syncthreads();
        }
        wts[s] = alpha * ((s == 0) ? 1.f : sh[s-1]);
        if (s == 255) ainv_sh = sh[255];
        if (s < 6) rgbacc[s] = 0.f;
        float* xrow = &xs[s*40];
        if (inbox) {
            #pragma unroll
            for (int c = 0; c < 12; ++c) {
                const float* g = k0 + c*4096000 + base;
                xrow[c] = g[0]*w000 + g[DX]*w100 + g[DY]*w010 + g[1]*w001 +
                          g[DX+DY]*w110 + g[DX+1]*w101 + g[DY+1]*w011 + g[DX+DY+1]*w111;
            }
        } else {
            #pragma unroll
            for (int c = 0; c < 12; ++c) xrow[c] = 0.f;
        }
        xrow[12]=vx; xrow[13]=vy; xrow[14]=vz;
        const float v3[3] = {vx, vy, vz};
        #pragma unroll
        for (int i = 0; i < 3; ++i)
            #pragma unroll
            for (int p = 0; p < 4; ++p) {
                const float a = v3[i] * (float)(1 << p);
                xrow[15 + i*4 + p] = sinf(a);
                xrow[27 + i*4 + p] = cosf(a);
            }
        xrow[39] = 0.f;
    }
    __syncthreads();
    const int j = tid & 127, sb = tid >> 7;
    float w0c[40];
    #pragma unroll
    for (int k = 0; k < 39; ++k) w0c[k] = w0[k*128 + j];
    w0c[39] = 0.f;
    float w1c[128];
    #pragma unroll
    for (int k = 0; k < 128; ++k) w1c[k] = w1[k*128 + j];
    const float b0j = b0[j], b1j = b1[j];
    const float w2r0 = w2[j*3+0], w2r1 = w2[j*3+1], w2r2 = w2[j*3+2];
    const float b20 = b2[0], b21 = b2[1], b22 = b2[2];
    const int lane = tid & 63, halfw = (tid >> 6) & 1;
    for (int it = 0; it < 128; ++it) {
        const int s = it*2 + sb;
        const float4* xrow4 = (const float4*)(&xs[s*40]);
        float acc = b0j;
        #pragma unroll
        for (int q = 0; q < 10; ++q) {
            const float4 v = xrow4[q];
            acc = fmaf(v.x, w0c[q*4+0], acc); acc = fmaf(v.y, w0c[q*4+1], acc);
            acc = fmaf(v.z, w0c[q*4+2], acc); acc = fmaf(v.w, w0c[q*4+3], acc);
        }
        h0s[sb][j] = fmaxf(acc, 0.f);
        __syncthreads();
        float acc1 = b1j;
        const float4* h4 = (const float4*)(&h0s[sb][0]);
        #pragma unroll
        for (int q = 0; q < 32; ++q) {
            const float4 v = h4[q];
            acc1 = fmaf(v.x, w1c[q*4+0], acc1); acc1 = fmaf(v.y, w1c[q*4+1], acc1);
            acc1 = fmaf(v.z, w1c[q*4+2], acc1); acc1 = fmaf(v.w, w1c[q*4+3], acc1);
        }
        const float hv = fmaxf(acc1, 0.f);
        float p0 = hv*w2r0, p1 = hv*w2r1, p2 = hv*w2r2;
        #pragma unroll
        for (int off = 32; off > 0; off >>= 1) {
            p0 += __shfl_down(p0, off); p1 += __shfl_down(p1, off); p2 += __shfl_down(p2, off);
        }
        if (lane == 0) { red[sb][halfw][0]=p0; red[sb][halfw][1]=p1; red[sb][halfw][2]=p2; }
        __syncthreads();
        if (tid == sb*128) {
            const float r0 = red[sb][0][0]+red[sb][1][0]+b20;
            const float r1 = red[sb][0][1]+red[sb][1][1]+b21;
            const float r2 = red[sb][0][2]+red[sb][1][2]+b22;
            const float wgt = wts[s];
            rgbacc[sb*3+0] += wgt / (1.f + expf(-r0));
            rgbacc[sb*3+1] += wgt / (1.f + expf(-r1));
            rgbacc[sb*3+2] += wgt / (1.f + expf(-r2));
        }
    }
    __syncthreads();
    if (tid < 3) out[r*3 + tid] = rgbacc[tid] + rgbacc[3 + tid] + ainv_sh;
}

extern "C" void kernel_launch(void* const* d_in, const int* in_sizes, int n_in,
                              void* d_out, int out_size, void* d_ws, size_t ws_size,
                              hipStream_t stream)
{
    const float* rays_o = (const float*)d_in[0];
    const float* rays_d = (const float*)d_in[1];
    const float* dens   = (const float*)d_in[2];
    const float* k0     = (const float*)d_in[3];
    const float* w0     = (const float*)d_in[4];
    const float* b0     = (const float*)d_in[5];
    const float* w1     = (const float*)d_in[6];
    const float* b1     = (const float*)d_in[7];
    const float* w2     = (const float*)d_in[8];
    const float* b2     = (const float*)d_in[9];
    float* out = (float*)d_out;
    const int N = in_sizes[0] / 3;

    if (ws_size >= WS_NEED) {
        unsigned short* gp  = (unsigned short*)d_ws;
        unsigned short* wpk = (unsigned short*)((char*)d_ws + W0P_OFF);
        repack_all<<<dim3(16011), dim3(256), 0, stream>>>(dens, k0, w0, w1, w2, gp, wpk);
        dvgo_mfma<<<dim3(N), dim3(256), 0, stream>>>(rays_o, rays_d, w0, b0, b1, b2,
                                                     gp, wpk, out);
    } else {
        dvgo_render<<<dim3(N), dim3(256), 0, stream>>>(rays_o, rays_d, dens, k0,
                                                       w0, b0, w1, b1, w2, b2, out);
    }
}

// Round 5
// 513.243 us; speedup vs baseline: 3.7080x; 1.0039x over previous
//
#include <hip/hip_runtime.h>
#include <hip/hip_bf16.h>
#include <math.h>

#define ACT_SHIFT_F (-13.8155095579637744f)
#define GRID_VOX 4096000
#define GP_BYTES  (GRID_VOX * 32)          // bf16 x16 channels per voxel
#define W0P_OFF   GP_BYTES                 // 8 frags  * 1024B
#define W1P_OFF   (W0P_OFF + 8 * 1024)     // 32 frags * 1024B
#define W2P_OFF   (W1P_OFF + 32 * 1024)    // 4 frags  * 1024B
#define WS_NEED   ((size_t)(W2P_OFF + 4 * 1024))

typedef __bf16 bf16x8 __attribute__((ext_vector_type(8)));
typedef float  f32x4  __attribute__((ext_vector_type(4)));
typedef float  fv4    __attribute__((ext_vector_type(4)));   // clang vector (nontemporal-ok)

__device__ __forceinline__ float bfu(unsigned short b) {
    return __uint_as_float(((unsigned int)b) << 16);
}
__device__ __forceinline__ unsigned short f2bf(float x) {   // RNE
    unsigned int u = __float_as_uint(x);
    u += 0x7fffu + ((u >> 16) & 1u);
    return (unsigned short)(u >> 16);
}
// truncation pack: a -> low16, b -> high16 (grid only; |rel err| <= 2^-8)
__device__ __forceinline__ unsigned int packtr(float a, float b) {
    return (__float_as_uint(a) >> 16) | (__float_as_uint(b) & 0xffff0000u);
}
#define UNPK(u, lo, hi) { lo = __uint_as_float((u) << 16); hi = __uint_as_float((u) & 0xffff0000u); }

__device__ __constant__ int offv_c[8] = {0, 1, 160, 161, 25600, 25601, 25760, 25761};

// ---------------- repack (fused): grid -> interleaved bf16 [vox][16]; W -> B-frags ----
// blocks [0,4000): 4 voxels/thread, float4 streams. blocks [4000,4011): weight frags.
__global__ void repack_all(const float* __restrict__ dens, const float* __restrict__ k0,
                           const float* __restrict__ w0, const float* __restrict__ w1,
                           const float* __restrict__ w2,
                           unsigned short* __restrict__ gp, unsigned short* __restrict__ wp)
{
    const int b = blockIdx.x;
    if (b < 4000) {
        const int v4 = b * 1024 + threadIdx.x * 4;       // 4 consecutive voxels
        const fv4 d4 = __builtin_nontemporal_load((const fv4*)(dens + v4));
        fv4 c4[12];
        #pragma unroll
        for (int c = 0; c < 12; ++c)
            c4[c] = __builtin_nontemporal_load((const fv4*)(k0 + (size_t)c * GRID_VOX + v4));
        uint4* dst = (uint4*)(gp + (size_t)v4 * 16);
        #pragma unroll
        for (int j = 0; j < 4; ++j) {
            const float* cj = &((const float*)c4)[j];     // c4[c] component j at cj[4*c]
            uint4 q0, q1;
            q0.x = packtr(d4[j],    cj[0]);
            q0.y = packtr(cj[4*1],  cj[4*2]);
            q0.z = packtr(cj[4*3],  cj[4*4]);
            q0.w = packtr(cj[4*5],  cj[4*6]);
            q1.x = packtr(cj[4*7],  cj[4*8]);
            q1.y = packtr(cj[4*9],  cj[4*10]);
            q1.z = packtr(cj[4*11], 0.f);
            q1.w = 0u;
            dst[j*2 + 0] = q0;
            dst[j*2 + 1] = q1;
        }
        return;
    }
    // ---- weight repack: B-frag (16x16x32): lane l holds B[k=(l>>4)*8+j][n=l&15] ----
    const int t = (b - 4000) * 256 + threadIdx.x;
    if (t >= 44 * 64) return;
    const int f = t >> 6, l = t & 63;
    const int n16 = l & 15, kg = l >> 4;
    unsigned short v[8];
    if (f < 8) {                       // W0: ntile=f, K=32 (feature rows 0..11 real)
        const int n = f * 16 + n16;
        #pragma unroll
        for (int j = 0; j < 8; ++j) {
            const int k = kg * 8 + j;
            v[j] = (k < 12) ? f2bf(w0[k * 128 + n]) : (unsigned short)0;
        }
    } else if (f < 40) {               // W1: frag (nt, ks)
        const int ff = f - 8, nt = ff >> 2, ks = ff & 3;
        const int n = nt * 16 + n16;
        #pragma unroll
        for (int j = 0; j < 8; ++j) {
            const int k = ks * 32 + kg * 8 + j;
            v[j] = f2bf(w1[k * 128 + n]);
        }
    } else {                           // W2: N=16 (cols 0..2 real), frag ks
        const int ks = f - 40;
        #pragma unroll
        for (int j = 0; j < 8; ++j) {
            const int k = ks * 32 + kg * 8 + j;
            v[j] = (n16 < 3) ? f2bf(w2[k * 3 + n16]) : (unsigned short)0;
        }
    }
    uint4 q;
    q.x = v[0] | (v[1] << 16); q.y = v[2] | (v[3] << 16);
    q.z = v[4] | (v[5] << 16); q.w = v[6] | (v[7] << 16);
    *(uint4*)(wp + f * 512 + l * 8) = q;
}

// ---------------- main render: one block per ray ----------------
// - phase A computes density (hf=0's channel-0 accumulator) AND features: no
//   separate density gather.
// - transmittance: per-chunk shfl_up scan with LDS carry Tcs[ck] (4 barriers/chunk).
// - Hs rows [wv*32,+32) wave-private through L0/L1/L2 (no intra-MLP barriers);
//   L1 streams nt tiles (unroll 1) to keep live regs ~110 (R2 spilled 1GB).
__global__ __launch_bounds__(256, 3)
void dvgo_mfma(const float* __restrict__ rays_o, const float* __restrict__ rays_d,
               const float* __restrict__ w0, const float* __restrict__ b0,
               const float* __restrict__ b1, const float* __restrict__ b2,
               const unsigned short* __restrict__ gp,   // packed grid
               const unsigned short* __restrict__ wpk,  // packed weights
               float* __restrict__ out)
{
    __shared__ unsigned short Xs[128 * 40];   // 12 feat + 20 zero pad, stride 40 bf16
    __shared__ unsigned short Hs[128 * 136];  // 128 + 8 pad, stride 136 bf16
    __shared__ float shA[128];                // per-chunk (1-alpha)
    __shared__ float wts[128];                // alpha, then final weights
    __shared__ float b0eff[128];
    __shared__ float b1s[128];
    __shared__ float vemb[28];
    __shared__ float red[4][3];
    __shared__ float b2s[3];
    __shared__ float Tcs[3];                  // carry: T before chunk ck; Tcs[2]=ainv
    __shared__ float spart;                   // wave0 scan total

    const int r = blockIdx.x, t = threadIdx.x;
    const int l = t & 63, wv = t >> 6;
    const int col = l & 15, rg = l >> 4;

    const float ox = rays_o[r*3+0], oy = rays_o[r*3+1], oz = rays_o[r*3+2];
    const float dxr = rays_d[r*3+0], dyr = rays_d[r*3+1], dzr = rays_d[r*3+2];
    const float rn = rsqrtf(dxr*dxr + dyr*dyr + dzr*dzr);
    const float vx = dxr*rn, vy = dyr*rn, vz = dzr*rn;

    // ---- phase 0: vemb, biases ----
    if (t < 27) {
        float val;
        if (t < 3) val = (t == 0) ? vx : ((t == 1) ? vy : vz);
        else {
            int q = t - 3;
            const bool is_sin = q < 12;
            if (!is_sin) q -= 12;
            const int i = q >> 2, p = q & 3;
            const float a = ((i == 0) ? vx : ((i == 1) ? vy : vz)) * (float)(1 << p);
            val = is_sin ? sinf(a) : cosf(a);
        }
        vemb[t] = val;
    }
    if (t < 3)   b2s[t] = b2[t];
    if (t < 128) b1s[t] = b1[t];
    if (t == 0)  Tcs[0] = 1.f;
    __syncthreads();

    if (t < 128) {                       // fold view embedding into layer-0 bias
        float a = b0[t];
        #pragma unroll
        for (int k = 0; k < 27; ++k) a = fmaf(vemb[k], w0[(12 + k) * 128 + t], a);
        b0eff[t] = a;
    }
    // X zero region: cols 12..31 (dwords 6..15 of each 20-dword row)
    for (int i = t; i < 128 * 10; i += 256) {
        const int row = i / 10, c = i % 10;
        ((unsigned int*)Xs)[row * 20 + 6 + c] = 0u;
    }
    // (b0eff/Xs-zero visible to L0 after the phase-A + scan barriers below)

    const unsigned short* w0p = wpk;
    const unsigned short* w1p = wpk + 8 * 512;
    const unsigned short* w2p = wpk + 40 * 512;
    const uint4* gq = (const uint4*)gp;

    float pacc = 0.f;   // per-lane weighted-rgb accumulator (cols 0..2 meaningful)

    #pragma unroll 1
    for (int ck = 0; ck < 2; ++ck) {
        // ---- phase A: gather features + density -> X rows, alpha ----
        {
            const int sl = t >> 1, hf = t & 1;
            const int s = ck * 128 + sl;
            const float tp = 0.05f + (1.95f / 255.f) * (float)s;
            const float px = ox + vx*tp, py = oy + vy*tp, pz = oz + vz*tp;
            const bool inbox = (px >= -1.f) & (px <= 1.f) & (py >= -1.f) & (py <= 1.f) &
                               (pz >= -1.f) & (pz <= 1.f);
            unsigned short* xrow = &Xs[sl * 40];
            if (inbox) {
                const float ix = fminf(fmaxf((px + 1.f) * 79.5f, 0.f), 159.f);
                const float iy = fminf(fmaxf((py + 1.f) * 79.5f, 0.f), 159.f);
                const float iz = fminf(fmaxf((pz + 1.f) * 79.5f, 0.f), 159.f);
                const int x0 = min((int)ix, 158), y0 = min((int)iy, 158), z0 = min((int)iz, 158);
                const float fx = ix - x0, fy = iy - y0, fz = iz - z0;
                const float gx = 1.f - fx, gy = 1.f - fy, gz = 1.f - fz;
                const int base = (x0 * 160 + y0) * 160 + z0;
                float w8[8];
                w8[0]=gx*gy*gz; w8[1]=gx*gy*fz; w8[2]=gx*fy*gz; w8[3]=gx*fy*fz;
                w8[4]=fx*gy*gz; w8[5]=fx*gy*fz; w8[6]=fx*fy*gz; w8[7]=fx*fy*fz;
                float a0=0,a1=0,a2=0,a3=0,a4=0,a5=0,a6=0,a7=0;
                #pragma unroll
                for (int cn = 0; cn < 8; ++cn) {
                    const uint4 q = gq[(size_t)(base + offv_c[cn]) * 2 + hf];
                    float f0,f1,f2,f3,f4,f5,f6,f7;
                    UNPK(q.x, f0, f1); UNPK(q.y, f2, f3);
                    UNPK(q.z, f4, f5); UNPK(q.w, f6, f7);
                    const float wc = w8[cn];
                    a0=fmaf(wc,f0,a0); a1=fmaf(wc,f1,a1); a2=fmaf(wc,f2,a2); a3=fmaf(wc,f3,a3);
                    a4=fmaf(wc,f4,a4); a5=fmaf(wc,f5,a5); a6=fmaf(wc,f6,a6); a7=fmaf(wc,f7,a7);
                }
                if (hf == 0) {   // slots 0..7 = [dens, feat0..6]; a0 = density trilerp
                    xrow[0]=f2bf(a1); xrow[1]=f2bf(a2); xrow[2]=f2bf(a3); xrow[3]=f2bf(a4);
                    xrow[4]=f2bf(a5); xrow[5]=f2bf(a6); xrow[6]=f2bf(a7);
                    const float e = expf(a0 + ACT_SHIFT_F);
                    const float op = 1.f + e;
                    const float alpha = e / (op + sqrtf(op));   // 1-(1+e)^(-1/2)
                    wts[sl] = alpha;
                    shA[sl] = 1.f - alpha;
                } else {         // slots 8..15 = [feat7..11, pad] -> x cols 7..11
                    xrow[7]=f2bf(a0); xrow[8]=f2bf(a1); xrow[9]=f2bf(a2);
                    xrow[10]=f2bf(a3); xrow[11]=f2bf(a4);
                }
            } else {
                if (hf == 0) {
                    #pragma unroll
                    for (int j = 0; j < 7; ++j) xrow[j] = 0;
                    wts[sl] = 0.f;
                    shA[sl] = 1.f;
                } else {
                    #pragma unroll
                    for (int j = 7; j < 12; ++j) xrow[j] = 0;
                }
            }
        }
        __syncthreads();   // Xs/shA/alpha complete

        // ---- transmittance scan (threads 0..127 = waves 0,1), carry Tcs[ck] ----
        float v = 1.f;
        if (t < 128) {
            v = shA[t];
            #pragma unroll
            for (int off = 1; off < 64; off <<= 1) {
                const float u = __shfl_up(v, off);
                if (l >= off) v *= u;
            }
            if (wv == 0 && l == 63) spart = v;
        }
        __syncthreads();   // spart visible
        if (t < 128) {
            float excl = __shfl_up(v, 1);
            if (l == 0) excl = 1.f;
            float E = Tcs[ck];
            const float sp = spart;
            if (wv == 1) E *= sp;
            const float w = wts[t] * E * excl;
            wts[t] = w;
            if (t == 127) Tcs[ck + 1] = Tcs[ck] * sp * v;
        }
        __syncthreads();   // wts final, visible to all waves

        const int row0 = wv * 32;   // this wave owns sample-rows [row0, row0+32)

        // ---- layer 0: H0 = relu(X*W0 + b0eff), K=32; wave-private Hs writes ----
        {
            bf16x8 A0[2];
            #pragma unroll
            for (int mt = 0; mt < 2; ++mt)
                A0[mt] = *(const bf16x8*)(&Xs[(row0 + mt * 16 + col) * 40 + rg * 8]);
            #pragma unroll 1
            for (int nt = 0; nt < 8; ++nt) {
                const bf16x8 B = *(const bf16x8*)(w0p + nt * 512 + l * 8);
                const float bias = b0eff[nt * 16 + col];
                #pragma unroll
                for (int mt = 0; mt < 2; ++mt) {
                    f32x4 acc = {0.f, 0.f, 0.f, 0.f};
                    acc = __builtin_amdgcn_mfma_f32_16x16x32_bf16(A0[mt], B, acc, 0, 0, 0);
                    #pragma unroll
                    for (int q = 0; q < 4; ++q) {
                        const float vv = fmaxf(acc[q] + bias, 0.f);
                        const float vo = __shfl_xor(vv, 1);
                        if ((l & 1) == 0) {
                            const int row = row0 + mt * 16 + rg * 4 + q;
                            const unsigned int pk = (unsigned int)f2bf(vv) |
                                                    ((unsigned int)f2bf(vo) << 16);
                            *(unsigned int*)(&Hs[row * 136 + nt * 16 + col]) = pk;
                        }
                    }
                }
            }
        }
        // (no barrier: Hs rows wave-private)

        // ---- layer 1: H1 = relu(H0*W1 + b1), K=128, in-place, nt streamed ----
        {
            bf16x8 A1[2][4];
            #pragma unroll
            for (int mt = 0; mt < 2; ++mt)
                #pragma unroll
                for (int ks = 0; ks < 4; ++ks)
                    A1[mt][ks] = *(const bf16x8*)(&Hs[(row0 + mt * 16 + col) * 136 + ks * 32 + rg * 8]);
            #pragma unroll 1
            for (int nt = 0; nt < 8; ++nt) {
                bf16x8 Bk[4];
                #pragma unroll
                for (int ks = 0; ks < 4; ++ks)
                    Bk[ks] = *(const bf16x8*)(w1p + (nt * 4 + ks) * 512 + l * 8);
                const float bias = b1s[nt * 16 + col];
                #pragma unroll
                for (int mt = 0; mt < 2; ++mt) {
                    f32x4 acc = {0.f, 0.f, 0.f, 0.f};
                    #pragma unroll
                    for (int ks = 0; ks < 4; ++ks)
                        acc = __builtin_amdgcn_mfma_f32_16x16x32_bf16(A1[mt][ks], Bk[ks], acc, 0, 0, 0);
                    #pragma unroll
                    for (int q = 0; q < 4; ++q) {
                        const float vv = fmaxf(acc[q] + bias, 0.f);
                        const float vo = __shfl_xor(vv, 1);
                        if ((l & 1) == 0) {
                            const int row = row0 + mt * 16 + rg * 4 + q;
                            const unsigned int pk = (unsigned int)f2bf(vv) |
                                                    ((unsigned int)f2bf(vo) << 16);
                            *(unsigned int*)(&Hs[row * 136 + nt * 16 + col]) = pk;
                        }
                    }
                }
            }
        }
        // (no barrier: still wave-private)

        // ---- layer 2 + epilogue: rgb = sigmoid(H1*W2 + b2); pacc += wts*rgb ----
        {
            bf16x8 Bk[4];
            #pragma unroll
            for (int ks = 0; ks < 4; ++ks)
                Bk[ks] = *(const bf16x8*)(w2p + ks * 512 + l * 8);
            const float bias2 = (col < 3) ? b2s[col] : 0.f;
            #pragma unroll
            for (int mt = 0; mt < 2; ++mt) {
                bf16x8 A2[4];
                #pragma unroll
                for (int ks = 0; ks < 4; ++ks)
                    A2[ks] = *(const bf16x8*)(&Hs[(row0 + mt * 16 + col) * 136 + ks * 32 + rg * 8]);
                f32x4 acc = {0.f, 0.f, 0.f, 0.f};
                #pragma unroll
                for (int ks = 0; ks < 4; ++ks)
                    acc = __builtin_amdgcn_mfma_f32_16x16x32_bf16(A2[ks], Bk[ks], acc, 0, 0, 0);
                #pragma unroll
                for (int q = 0; q < 4; ++q) {
                    const float rv = acc[q] + bias2;
                    const float sg = 1.f / (1.f + expf(-rv));
                    const int srow = row0 + mt * 16 + rg * 4 + q;
                    pacc = fmaf(wts[srow], sg, pacc);
                }
            }
        }
        __syncthreads();   // Xs/shA/wts safe to rewrite next chunk
    }

    // reduce pacc over the 4 row-groups (lanes sharing a column)
    pacc += __shfl_xor(pacc, 16);
    pacc += __shfl_xor(pacc, 32);
    if (rg == 0 && col < 3) red[wv][col] = pacc;
    __syncthreads();
    if (t < 3) out[r * 3 + t] = red[0][t] + red[1][t] + red[2][t] + red[3][t] + Tcs[2];
}

// ---------------- fallback (round-1 kernel) if ws too small ----------------
__global__ __launch_bounds__(256, 2)
void dvgo_render(const float* __restrict__ rays_o, const float* __restrict__ rays_d,
                 const float* __restrict__ dens, const float* __restrict__ k0,
                 const float* __restrict__ w0, const float* __restrict__ b0,
                 const float* __restrict__ w1, const float* __restrict__ b1,
                 const float* __restrict__ w2, const float* __restrict__ b2,
                 float* __restrict__ out)
{
    __shared__ float xs[256 * 40];
    __shared__ float sh[256];
    __shared__ float wts[256];
    __shared__ float h0s[2][128];
    __shared__ float red[2][2][3];
    __shared__ float rgbacc[6];
    __shared__ float ainv_sh;

    const int r = blockIdx.x, tid = threadIdx.x;
    {
        const int s = tid;
        const float ox = rays_o[r*3+0], oy = rays_o[r*3+1], oz = rays_o[r*3+2];
        const float dxr = rays_d[r*3+0], dyr = rays_d[r*3+1], dzr = rays_d[r*3+2];
        const float rn = rsqrtf(dxr*dxr + dyr*dyr + dzr*dzr);
        const float vx = dxr*rn, vy = dyr*rn, vz = dzr*rn;
        const float t = 0.05f + 1.95f * (1.0f/255.0f) * (float)s;
        const float px = ox + vx*t, py = oy + vy*t, pz = oz + vz*t;
        const bool inbox = (px >= -1.f) && (px <= 1.f) && (py >= -1.f) && (py <= 1.f) &&
                           (pz >= -1.f) && (pz <= 1.f);
        const float ix = fminf(fmaxf((px + 1.f) * 79.5f, 0.f), 159.f);
        const float iy = fminf(fmaxf((py + 1.f) * 79.5f, 0.f), 159.f);
        const float iz = fminf(fmaxf((pz + 1.f) * 79.5f, 0.f), 159.f);
        const int x0 = min((int)ix, 158), y0 = min((int)iy, 158), z0 = min((int)iz, 158);
        const float fx = ix - x0, fy = iy - y0, fz = iz - z0;
        const float gx = 1.f - fx, gy = 1.f - fy, gz = 1.f - fz;
        const int DX = 25600, DY = 160;
        const int base = (x0*160 + y0)*160 + z0;
        const float w000=gx*gy*gz, w100=fx*gy*gz, w010=gx*fy*gz, w001=gx*gy*fz;
        const float w110=fx*fy*gz, w101=fx*gy*fz, w011=gx*fy*fz, w111=fx*fy*fz;
        float alpha = 0.f;
        if (inbox) {
            const float d = dens[base]*w000 + dens[base+DX]*w100 + dens[base+DY]*w010 +
                            dens[base+1]*w001 + dens[base+DX+DY]*w110 + dens[base+DX+1]*w101 +
                            dens[base+DY+1]*w011 + dens[base+DX+DY+1]*w111;
            const float e = expf(d + ACT_SHIFT_F);
            const float op = 1.f + e;
            alpha = e / (op + sqrtf(op));
        }
        sh[s] = 1.f - alpha;
        __syncthreads();
        #pragma unroll
        for (int off = 1; off < 256; off <<= 1) {
            const float v = (s >= off) ? sh[s - off] : 1.f;
            __syncthreads();
            sh[s] *= v;
            __syncthreads();
        }
        wts[s] = alpha * ((s == 0) ? 1.f : sh[s-1]);
        if (s == 255) ainv_sh = sh[255];
        if (s < 6) rgbacc[s] = 0.f;
        float* xrow = &xs[s*40];
        if (inbox) {
            #pragma unroll
            for (int c = 0; c < 12; ++c) {
                const float* g = k0 + c*4096000 + base;
                xrow[c] = g[0]*w000 + g[DX]*w100 + g[DY]*w010 + g[1]*w001 +
                          g[DX+DY]*w110 + g[DX+1]*w101 + g[DY+1]*w011 + g[DX+DY+1]*w111;
            }
        } else {
            #pragma unroll
            for (int c = 0; c < 12; ++c) xrow[c] = 0.f;
        }
        xrow[12]=vx; xrow[13]=vy; xrow[14]=vz;
        const float v3[3] = {vx, vy, vz};
        #pragma unroll
        for (int i = 0; i < 3; ++i)
            #pragma unroll
            for (int p = 0; p < 4; ++p) {
                const float a = v3[i] * (float)(1 << p);
                xrow[15 + i*4 + p] = sinf(a);
                xrow[27 + i*4 + p] = cosf(a);
            }
        xrow[39] = 0.f;
    }
    __syncthreads();
    const int j = tid & 127, sb = tid >> 7;
    float w0c[40];
    #pragma unroll
    for (int k = 0; k < 39; ++k) w0c[k] = w0[k*128 + j];
    w0c[39] = 0.f;
    float w1c[128];
    #pragma unroll
    for (int k = 0; k < 128; ++k) w1c[k] = w1[k*128 + j];
    const float b0j = b0[j], b1j = b1[j];
    const float w2r0 = w2[j*3+0], w2r1 = w2[j*3+1], w2r2 = w2[j*3+2];
    const float b20 = b2[0], b21 = b2[1], b22 = b2[2];
    const int lane = tid & 63, halfw = (tid >> 6) & 1;
    for (int it = 0; it < 128; ++it) {
        const int s = it*2 + sb;
        const float4* xrow4 = (const float4*)(&xs[s*40]);
        float acc = b0j;
        #pragma unroll
        for (int q = 0; q < 10; ++q) {
            const float4 v = xrow4[q];
            acc = fmaf(v.x, w0c[q*4+0], acc); acc = fmaf(v.y, w0c[q*4+1], acc);
            acc = fmaf(v.z, w0c[q*4+2], acc); acc = fmaf(v.w, w0c[q*4+3], acc);
        }
        h0s[sb][j] = fmaxf(acc, 0.f);
        __syncthreads();
        float acc1 = b1j;
        const float4* h4 = (const float4*)(&h0s[sb][0]);
        #pragma unroll
        for (int q = 0; q < 32; ++q) {
            const float4 v = h4[q];
            acc1 = fmaf(v.x, w1c[q*4+0], acc1); acc1 = fmaf(v.y, w1c[q*4+1], acc1);
            acc1 = fmaf(v.z, w1c[q*4+2], acc1); acc1 = fmaf(v.w, w1c[q*4+3], acc1);
        }
        const float hv = fmaxf(acc1, 0.f);
        float p0 = hv*w2r0, p1 = hv*w2r1, p2 = hv*w2r2;
        #pragma unroll
        for (int off = 32; off > 0; off >>= 1) {
            p0 += __shfl_down(p0, off); p1 += __shfl_down(p1, off); p2 += __shfl_down(p2, off);
        }
        if (lane == 0) { red[sb][halfw][0]=p0; red[sb][halfw][1]=p1; red[sb][halfw][2]=p2; }
        __syncthreads();
        if (tid == sb*128) {
            const float r0 = red[sb][0][0]+red[sb][1][0]+b20;
            const float r1 = red[sb][0][1]+red[sb][1][1]+b21;
            const float r2 = red[sb][0][2]+red[sb][1][2]+b22;
            const float wgt = wts[s];
            rgbacc[sb*3+0] += wgt / (1.f + expf(-r0));
            rgbacc[sb*3+1] += wgt / (1.f + expf(-r1));
            rgbacc[sb*3+2] += wgt / (1.f + expf(-r2));
        }
    }
    __syncthreads();
    if (tid < 3) out[r*3 + tid] = rgbacc[tid] + rgbacc[3 + tid] + ainv_sh;
}

extern "C" void kernel_launch(void* const* d_in, const int* in_sizes, int n_in,
                              void* d_out, int out_size, void* d_ws, size_t ws_size,
                              hipStream_t stream)
{
    const float* rays_o = (const float*)d_in[0];
    const float* rays_d = (const float*)d_in[1];
    const float* dens   = (const float*)d_in[2];
    const float* k0     = (const float*)d_in[3];
    const float* w0     = (const float*)d_in[4];
    const float* b0     = (const float*)d_in[5];
    const float* w1     = (const float*)d_in[6];
    const float* b1     = (const float*)d_in[7];
    const float* w2     = (const float*)d_in[8];
    const float* b2     = (const float*)d_in[9];
    float* out = (float*)d_out;
    const int N = in_sizes[0] / 3;

    if (ws_size >= WS_NEED) {
        unsigned short* gp  = (unsigned short*)d_ws;
        unsigned short* wpk = (unsigned short*)((char*)d_ws + W0P_OFF);
        repack_all<<<dim3(4011), dim3(256), 0, stream>>>(dens, k0, w0, w1, w2, gp, wpk);
        dvgo_mfma<<<dim3(N), dim3(256), 0, stream>>>(rays_o, rays_d, w0, b0, b1, b2,
                                                     gp, wpk, out);
    } else {
        dvgo_render<<<dim3(N), dim3(256), 0, stream>>>(rays_o, rays_d, dens, k0,
                                                       w0, b0, w1, b1, w2, b2, out);
    }
}